// Round 1
// baseline (230.623 us; speedup 1.0000x reference)
//
#include <hip/hip_runtime.h>

// Problem: Rec1_43748536877661 — diagonal SSM block on MI355X (gfx950)
// B=2, S=2048, D=128, N=2048.  fp32 in/out, bf16 internal compute (tol 2.14e-2).
//
// Pipeline (6 kernels):
//  1. prep:       fp32->bf16 convert x, W_B/W_dt/W_C (packed), W_out; Aval=-exp(A_log)
//  2. proj:       MFMA bf16 GEMM (M=4096,K=128) x3 fused epilogue -> abar,bbar,c (bf16)
//  3. scan_local: per-chunk (CH=64) prefix: P=prod(a), HL=local scan end state
//  4. scan_carry: sequential over 32 chunks -> init state per chunk
//  5. scan_apply: replay chunk with true init, y = c*h (bf16)
//  6. outproj:    MFMA bf16 GEMM (M=4096,K=2048,N=128) + b_out -> fp32 out

#define BB 2
#define SS 2048
#define DDIM 128
#define NDIM 2048
#define TT (BB*SS)      // 4096 tokens
#define CH 64
#define NCH (SS/CH)     // 32 chunks

typedef short short8 __attribute__((ext_vector_type(8)));
typedef float floatx4 __attribute__((ext_vector_type(4)));

__device__ __forceinline__ unsigned short f2b(float f){
  unsigned u = __float_as_uint(f);
  u += 0x7FFFu + ((u >> 16) & 1u);   // round-to-nearest-even
  return (unsigned short)(u >> 16);
}
__device__ __forceinline__ float b2f(unsigned short h){
  return __uint_as_float(((unsigned)h) << 16);
}
__device__ __forceinline__ float softplus_f(float v){
  return v > 15.f ? v : log1pf(__expf(v));
}

// ---------------- 1. prep: fp32 -> bf16 conversions ----------------
__global__ void prep_kernel(const float* __restrict__ x,
                            const float* __restrict__ W_B,
                            const float* __restrict__ W_dt,
                            const float* __restrict__ W_C,
                            const float* __restrict__ A_log,
                            const float* __restrict__ W_out,
                            unsigned short* __restrict__ xb,
                            unsigned short* __restrict__ Wb3,
                            unsigned short* __restrict__ Wob,
                            float* __restrict__ Aval){
  int i = blockIdx.x * blockDim.x + threadIdx.x;
  if (i < TT*DDIM) xb[i] = f2b(x[i]);
  if (i < NDIM*DDIM){
    Wb3[i]               = f2b(W_B[i]);
    Wb3[NDIM*DDIM + i]   = f2b(W_dt[i]);
    Wb3[2*NDIM*DDIM + i] = f2b(W_C[i]);
    Wob[i]               = f2b(W_out[i]);
  }
  if (i < NDIM) Aval[i] = -expf(A_log[i]);
}

// ---------------- 2. fused projections via MFMA ----------------
// grid (TT/64, NDIM/16), block 256 (4 waves). Wave w: tokens [t0+w*16, +16) x 16 n.
__global__ void proj_kernel(const unsigned short* __restrict__ xb,
                            const unsigned short* __restrict__ Wb3,
                            const float* __restrict__ b_B,
                            const float* __restrict__ b_dt,
                            const float* __restrict__ b_C,
                            const float* __restrict__ Aval,
                            unsigned short* __restrict__ abar,
                            unsigned short* __restrict__ bbar,
                            unsigned short* __restrict__ cf){
  const int lane = threadIdx.x & 63;
  const int wv   = threadIdx.x >> 6;
  const int m    = lane & 15;     // A: token row   / B: n col
  const int q    = lane >> 4;     // k-group
  const int t0   = blockIdx.x * 64 + wv * 16;
  const int n0   = blockIdx.y * 16;

  const unsigned short* xrow = xb  + (size_t)(t0 + m) * DDIM + q*8;
  const unsigned short* wB   = Wb3 + (size_t)(n0 + m) * DDIM + q*8;
  const unsigned short* wD   = wB + (size_t)NDIM*DDIM;
  const unsigned short* wC   = wD + (size_t)NDIM*DDIM;

  floatx4 aB = {0.f,0.f,0.f,0.f};
  floatx4 aD = aB, aC = aB;
#pragma unroll
  for (int kk = 0; kk < DDIM/32; ++kk){
    short8 av = *(const short8*)(xrow + kk*32);
    short8 vB = *(const short8*)(wB + kk*32);
    short8 vD = *(const short8*)(wD + kk*32);
    short8 vC = *(const short8*)(wC + kk*32);
    aB = __builtin_amdgcn_mfma_f32_16x16x32_bf16(av, vB, aB, 0, 0, 0);
    aD = __builtin_amdgcn_mfma_f32_16x16x32_bf16(av, vD, aD, 0, 0, 0);
    aC = __builtin_amdgcn_mfma_f32_16x16x32_bf16(av, vC, aC, 0, 0, 0);
  }
  const int n = n0 + m;
  const float bBv = b_B[n], bDv = b_dt[n], bCv = b_C[n], Av = Aval[n];
#pragma unroll
  for (int r = 0; r < 4; ++r){
    const int t = t0 + q*4 + r;            // D row = (lane>>4)*4 + r
    float dtv = softplus_f(aD[r] + bDv);
    float ab  = __expf(dtv * Av);
    float bb  = dtv * (aB[r] + bBv);
    float cc  = aC[r] + bCv;
    size_t o = (size_t)t * NDIM + n;       // D col = lane&15
    abar[o] = f2b(ab);
    bbar[o] = f2b(bb);
    cf[o]   = f2b(cc);
  }
}

// ---------------- 3. chunk-local scan ----------------
// grid (NDIM/512, NCH, BB), block 256; thread handles 2 consecutive n.
__global__ void scan_local_kernel(const unsigned short* __restrict__ abar,
                                  const unsigned short* __restrict__ bbar,
                                  float* __restrict__ P,
                                  float* __restrict__ HL){
  const int n = blockIdx.x * 512 + threadIdx.x * 2;
  const int c = blockIdx.y;
  const int b = blockIdx.z;
  size_t base = ((size_t)(b*SS + c*CH)) * NDIM + n;
  float p0=1.f, p1=1.f, h0=0.f, h1=0.f;
#pragma unroll 4
  for (int s = 0; s < CH; ++s){
    ushort2 a2 = *(const ushort2*)(abar + base);
    ushort2 b2 = *(const ushort2*)(bbar + base);
    float a0 = b2f(a2.x), a1 = b2f(a2.y);
    h0 = a0*h0 + b2f(b2.x);
    h1 = a1*h1 + b2f(b2.y);
    p0 *= a0; p1 *= a1;
    base += NDIM;
  }
  size_t o = ((size_t)(b*NCH + c)) * NDIM + n;
  float2 pv; pv.x = p0; pv.y = p1;
  float2 hv; hv.x = h0; hv.y = h1;
  *(float2*)(P  + o) = pv;
  *(float2*)(HL + o) = hv;
}

// ---------------- 4. carry across chunks ----------------
// 2048 threads total; thread handles (b, n..n+1), sequential over 32 chunks.
__global__ void scan_carry_kernel(const float* __restrict__ P,
                                  const float* __restrict__ HL,
                                  float* __restrict__ initb){
  const int gid = blockIdx.x * blockDim.x + threadIdx.x;   // 0..2047
  const int b = gid >> 10;
  const int n = (gid & 1023) * 2;
  size_t base = (size_t)b * NCH * NDIM + n;
  float c0 = 0.f, c1 = 0.f;
#pragma unroll
  for (int c = 0; c < NCH; ++c){
    float2 iv; iv.x = c0; iv.y = c1;
    *(float2*)(initb + base) = iv;
    float2 pp = *(const float2*)(P  + base);
    float2 hh = *(const float2*)(HL + base);
    c0 = pp.x*c0 + hh.x;
    c1 = pp.y*c1 + hh.y;
    base += NDIM;
  }
}

// ---------------- 5. apply: replay chunk with true init, emit y ----------------
__global__ void scan_apply_kernel(const unsigned short* __restrict__ abar,
                                  const unsigned short* __restrict__ bbar,
                                  const unsigned short* __restrict__ cf,
                                  const float* __restrict__ initb,
                                  unsigned short* __restrict__ yb){
  const int n = blockIdx.x * 512 + threadIdx.x * 2;
  const int c = blockIdx.y;
  const int b = blockIdx.z;
  size_t io = ((size_t)(b*NCH + c)) * NDIM + n;
  float2 iv = *(const float2*)(initb + io);
  float h0 = iv.x, h1 = iv.y;
  size_t base = ((size_t)(b*SS + c*CH)) * NDIM + n;
#pragma unroll 4
  for (int s = 0; s < CH; ++s){
    ushort2 a2 = *(const ushort2*)(abar + base);
    ushort2 b2 = *(const ushort2*)(bbar + base);
    ushort2 c2 = *(const ushort2*)(cf   + base);
    h0 = b2f(a2.x)*h0 + b2f(b2.x);
    h1 = b2f(a2.y)*h1 + b2f(b2.y);
    ushort2 yv;
    yv.x = f2b(b2f(c2.x)*h0);
    yv.y = f2b(b2f(c2.y)*h1);
    *(ushort2*)(yb + base) = yv;
    base += NDIM;
  }
}

// ---------------- 6. output projection via MFMA ----------------
// grid (TT/256, DDIM/16), block 256 (4 waves). Wave w: tokens [t0+w*64,+64) x 16 d.
__global__ void outproj_kernel(const unsigned short* __restrict__ yb,
                               const unsigned short* __restrict__ Wob,
                               const float* __restrict__ b_out,
                               float* __restrict__ out){
  const int lane = threadIdx.x & 63;
  const int wv   = threadIdx.x >> 6;
  const int m    = lane & 15;
  const int q    = lane >> 4;
  const int t0   = blockIdx.x * 256 + wv * 64;
  const int d0   = blockIdx.y * 16;

  const unsigned short* wrow = Wob + (size_t)(d0 + m) * NDIM + q*8;
  const unsigned short* y0   = yb  + (size_t)(t0 + m) * NDIM + q*8;

  floatx4 acc0 = {0.f,0.f,0.f,0.f};
  floatx4 acc1 = acc0, acc2 = acc0, acc3 = acc0;
#pragma unroll 4
  for (int kk = 0; kk < NDIM/32; ++kk){
    short8 bf = *(const short8*)(wrow + kk*32);
    short8 a0 = *(const short8*)(y0 + kk*32);
    short8 a1 = *(const short8*)(y0 + (size_t)16*NDIM + kk*32);
    short8 a2 = *(const short8*)(y0 + (size_t)32*NDIM + kk*32);
    short8 a3 = *(const short8*)(y0 + (size_t)48*NDIM + kk*32);
    acc0 = __builtin_amdgcn_mfma_f32_16x16x32_bf16(a0, bf, acc0, 0, 0, 0);
    acc1 = __builtin_amdgcn_mfma_f32_16x16x32_bf16(a1, bf, acc1, 0, 0, 0);
    acc2 = __builtin_amdgcn_mfma_f32_16x16x32_bf16(a2, bf, acc2, 0, 0, 0);
    acc3 = __builtin_amdgcn_mfma_f32_16x16x32_bf16(a3, bf, acc3, 0, 0, 0);
  }
  const int d = d0 + m;
  const float bo = b_out[d];
#pragma unroll
  for (int r = 0; r < 4; ++r){
    out[(size_t)(t0      + q*4 + r) * DDIM + d] = acc0[r] + bo;
    out[(size_t)(t0 + 16 + q*4 + r) * DDIM + d] = acc1[r] + bo;
    out[(size_t)(t0 + 32 + q*4 + r) * DDIM + d] = acc2[r] + bo;
    out[(size_t)(t0 + 48 + q*4 + r) * DDIM + d] = acc3[r] + bo;
  }
}

extern "C" void kernel_launch(void* const* d_in, const int* in_sizes, int n_in,
                              void* d_out, int out_size, void* d_ws, size_t ws_size,
                              hipStream_t stream) {
  const float* x     = (const float*)d_in[0];
  const float* W_B   = (const float*)d_in[1];
  const float* b_B   = (const float*)d_in[2];
  const float* W_C   = (const float*)d_in[3];
  const float* b_C   = (const float*)d_in[4];
  const float* W_dt  = (const float*)d_in[5];
  const float* b_dt  = (const float*)d_in[6];
  const float* A_log = (const float*)d_in[7];
  const float* W_out = (const float*)d_in[8];
  const float* b_out = (const float*)d_in[9];
  float* out = (float*)d_out;

  char* w = (char*)d_ws;
  unsigned short* xb    = (unsigned short*)(w + 0x0000000);  // 1 MB
  unsigned short* Wb3   = (unsigned short*)(w + 0x0100000);  // 1.5 MB [B,dt,C]
  unsigned short* Wob   = (unsigned short*)(w + 0x0280000);  // 0.5 MB
  float*          Aval  = (float*)         (w + 0x0300000);  // 8 KB
  unsigned short* abar  = (unsigned short*)(w + 0x0310000);  // 16 MB
  unsigned short* bbar  = (unsigned short*)(w + 0x1310000);  // 16 MB
  unsigned short* cf    = (unsigned short*)(w + 0x2310000);  // 16 MB
  unsigned short* yb    = (unsigned short*)(w + 0x3310000);  // 16 MB
  float*          Pbuf  = (float*)         (w + 0x4310000);  // 512 KB
  float*          HLbuf = (float*)         (w + 0x4390000);  // 512 KB
  float*          initb = (float*)         (w + 0x4410000);  // 512 KB
  // total ~72 MB

  prep_kernel<<<(TT*DDIM + 255)/256, 256, 0, stream>>>(
      x, W_B, W_dt, W_C, A_log, W_out, xb, Wb3, Wob, Aval);

  proj_kernel<<<dim3(TT/64, NDIM/16), 256, 0, stream>>>(
      xb, Wb3, b_B, b_dt, b_C, Aval, abar, bbar, cf);

  scan_local_kernel<<<dim3(NDIM/512, NCH, BB), 256, 0, stream>>>(
      abar, bbar, Pbuf, HLbuf);

  scan_carry_kernel<<<(BB*NDIM/2 + 255)/256, 256, 0, stream>>>(
      Pbuf, HLbuf, initb);

  scan_apply_kernel<<<dim3(NDIM/512, NCH, BB), 256, 0, stream>>>(
      abar, bbar, cf, initb, yb);

  outproj_kernel<<<dim3(TT/256, DDIM/16), 256, 0, stream>>>(
      yb, Wob, b_out, out);
}

// Round 2
// 145.340 us; speedup vs baseline: 1.5868x; 1.5868x over previous
//
#include <hip/hip_runtime.h>

// Rec1_43748536877661 — diagonal SSM block, MI355X gfx950.
// B=2,S=2048,D=128,N=2048. fp32 in/out, bf16 internal (tol 2.14e-2).
// R2: fragment-packed operands everywhere; proj uses A=W,B=x swap so stores are
// contiguous ushort4 along n; apply writes y in packed A-fragment layout.

#define BB 2
#define SS 2048
#define DDIM 128
#define NDIM 2048
#define TT (BB*SS)      // 4096 tokens
#define CH 32
#define NCH (SS/CH)     // 64 chunks

typedef short short8 __attribute__((ext_vector_type(8)));
typedef float floatx4 __attribute__((ext_vector_type(4)));

__device__ __forceinline__ unsigned short f2b(float f){
  unsigned u = __float_as_uint(f);
  u += 0x7FFFu + ((u >> 16) & 1u);
  return (unsigned short)(u >> 16);
}
__device__ __forceinline__ float b2f(unsigned short h){
  return __uint_as_float(((unsigned)h) << 16);
}
__device__ __forceinline__ float softplus_f(float v){
  return v > 15.f ? v : __logf(1.f + __expf(v));
}
__device__ __forceinline__ void pack8(const float* __restrict__ s,
                                      unsigned short* __restrict__ d){
  floatx4 v0 = *(const floatx4*)s;
  floatx4 v1 = *(const floatx4*)(s + 4);
  short8 r;
  r[0]=(short)f2b(v0[0]); r[1]=(short)f2b(v0[1]); r[2]=(short)f2b(v0[2]); r[3]=(short)f2b(v0[3]);
  r[4]=(short)f2b(v1[0]); r[5]=(short)f2b(v1[1]); r[6]=(short)f2b(v1[2]); r[7]=(short)f2b(v1[3]);
  *(short8*)d = r;
}

// ---------------- 1. prep: pack to MFMA fragment-linear layouts ----------------
// Fragment-linear (K=128): group g -> tile=g>>8, kk=(g>>6)&3, lane=g&63,
//   element M[tile*16 + (lane&15)][kk*32 + (lane>>4)*8 + j], dst = g*8+j.
// Fragment-linear (K=2048): tile=g>>12, kk=(g>>6)&63, lane=g&63, dst = g*8+j.
__global__ void prep_kernel(const float* __restrict__ x,
                            const float* __restrict__ W_B,
                            const float* __restrict__ W_C,
                            const float* __restrict__ W_dt,
                            const float* __restrict__ A_log,
                            const float* __restrict__ W_out,
                            unsigned short* __restrict__ xp,
                            unsigned short* __restrict__ Wp3,
                            unsigned short* __restrict__ Wop,
                            float* __restrict__ Aval){
  const int gid = blockIdx.x * blockDim.x + threadIdx.x;   // 0..98303
  if (gid < 2048) Aval[gid] = -__expf(A_log[gid]);
  // x: 65536 groups (256 t-tiles)
  if (gid < 65536){
    int g = gid, tile = g >> 8, kk = (g >> 6) & 3, lane = g & 63;
    int q = lane >> 4, m = lane & 15;
    pack8(x + (size_t)(tile*16 + m)*DDIM + kk*32 + q*8, xp + (size_t)g*8);
  }
  // W_B / W_dt / W_C: 3 x 32768 groups (128 n-tiles each)
  if (gid < 98304){
    int mat = gid >> 15, g = gid & 32767;
    const float* W = (mat == 0) ? W_B : (mat == 1 ? W_dt : W_C);
    int tile = g >> 8, kk = (g >> 6) & 3, lane = g & 63;
    int q = lane >> 4, m = lane & 15;
    pack8(W + (size_t)(tile*16 + m)*DDIM + kk*32 + q*8,
          Wp3 + (size_t)mat*262144 + (size_t)g*8);
  }
  // W_out: 32768 groups (8 d-tiles, K=2048)
  if (gid < 32768){
    int g = gid, tile = g >> 12, kk = (g >> 6) & 63, lane = g & 63;
    int q = lane >> 4, m = lane & 15;
    pack8(W_out + (size_t)(tile*16 + m)*NDIM + kk*32 + q*8, Wop + (size_t)g*8);
  }
}

// ---------------- 2. fused projections ----------------
// grid (TT/64, NDIM/64), block 256 (4 waves). Wave w: 16 t x 64 n x 3 mats.
// mfma(Wfrag, xfrag): D.row -> n (q*4+r), D.col -> t (m)  => lane holds 4
// consecutive n at fixed t => contiguous ushort4 stores.
__global__ void proj_kernel(const unsigned short* __restrict__ xp,
                            const unsigned short* __restrict__ Wp3,
                            const float* __restrict__ b_B,
                            const float* __restrict__ b_dt,
                            const float* __restrict__ b_C,
                            const float* __restrict__ Aval,
                            unsigned short* __restrict__ abar,
                            unsigned short* __restrict__ bbar,
                            unsigned short* __restrict__ cf){
  __shared__ unsigned short sW[3*8192];    // 48 KB: [mat][nt][kk][lane][8]
  const int tid  = threadIdx.x;
  const int lane = tid & 63;
  const int wv   = tid >> 6;
  const int m    = lane & 15;
  const int q    = lane >> 4;

  // stage packed weights for this n-block (4 consecutive n-tiles per mat)
#pragma unroll
  for (int mat = 0; mat < 3; ++mat){
    const unsigned short* src = Wp3 + (size_t)mat*262144 + (size_t)blockIdx.y*8192;
    unsigned short* dst = sW + mat*8192;
#pragma unroll
    for (int i = 0; i < 4; ++i){
      int e = (i*256 + tid) * 8;
      *(short8*)(dst + e) = *(const short8*)(src + e);
    }
  }
  __syncthreads();

  const int tileT = blockIdx.x*4 + wv;
  short8 xf[4];
#pragma unroll
  for (int kk = 0; kk < 4; ++kk)
    xf[kk] = *(const short8*)(xp + (size_t)tileT*2048 + kk*512 + lane*8);

  floatx4 acc[3][4];
#pragma unroll
  for (int mat = 0; mat < 3; ++mat)
#pragma unroll
    for (int nt = 0; nt < 4; ++nt)
      acc[mat][nt] = (floatx4){0.f,0.f,0.f,0.f};

#pragma unroll
  for (int mat = 0; mat < 3; ++mat)
#pragma unroll
    for (int nt = 0; nt < 4; ++nt)
#pragma unroll
      for (int kk = 0; kk < 4; ++kk){
        short8 wf = *(const short8*)(sW + mat*8192 + nt*2048 + kk*512 + lane*8);
        acc[mat][nt] = __builtin_amdgcn_mfma_f32_16x16x32_bf16(wf, xf[kk], acc[mat][nt], 0, 0, 0);
      }

  const int t  = tileT*16 + m;
  const int n0 = blockIdx.y*64;
#pragma unroll
  for (int nt = 0; nt < 4; ++nt){
    const int nb = n0 + nt*16 + q*4;
    floatx4 bB4 = *(const floatx4*)(b_B  + nb);
    floatx4 bD4 = *(const floatx4*)(b_dt + nb);
    floatx4 bC4 = *(const floatx4*)(b_C  + nb);
    floatx4 A4  = *(const floatx4*)(Aval + nb);
    ushort4 av, bv, cv;
    float dtv, ab, bbv, cc;
#pragma unroll
    for (int r = 0; r < 4; ++r){
      dtv = softplus_f(acc[1][nt][r] + bD4[r]);
      ab  = __expf(dtv * A4[r]);
      bbv = dtv * (acc[0][nt][r] + bB4[r]);
      cc  = acc[2][nt][r] + bC4[r];
      ((unsigned short*)&av)[r] = f2b(ab);
      ((unsigned short*)&bv)[r] = f2b(bbv);
      ((unsigned short*)&cv)[r] = f2b(cc);
    }
    size_t o = (size_t)t*NDIM + nb;
    *(ushort4*)(abar + o) = av;
    *(ushort4*)(bbar + o) = bv;
    *(ushort4*)(cf   + o) = cv;
  }
}

// ---------------- 3. chunk-local scan ----------------
// grid (NDIM/512, NCH, BB), block 256; thread: 2 consecutive n.
__global__ void scan_local_kernel(const unsigned short* __restrict__ abar,
                                  const unsigned short* __restrict__ bbar,
                                  float* __restrict__ P,
                                  float* __restrict__ HL){
  const int n = blockIdx.x*512 + threadIdx.x*2;
  const int c = blockIdx.y;
  const int b = blockIdx.z;
  size_t base = ((size_t)(b*SS + c*CH))*NDIM + n;
  float p0=1.f, p1=1.f, h0=0.f, h1=0.f;
#pragma unroll 8
  for (int s = 0; s < CH; ++s){
    ushort2 a2 = *(const ushort2*)(abar + base);
    ushort2 b2 = *(const ushort2*)(bbar + base);
    float a0 = b2f(a2.x), a1 = b2f(a2.y);
    h0 = a0*h0 + b2f(b2.x);
    h1 = a1*h1 + b2f(b2.y);
    p0 *= a0; p1 *= a1;
    base += NDIM;
  }
  size_t o = ((size_t)(b*NCH + c))*NDIM + n;
  float2 pv; pv.x = p0; pv.y = p1;
  float2 hv; hv.x = h0; hv.y = h1;
  *(float2*)(P  + o) = pv;
  *(float2*)(HL + o) = hv;
}

// ---------------- 4. carry across chunks ----------------
__global__ void scan_carry_kernel(const float* __restrict__ P,
                                  const float* __restrict__ HL,
                                  float* __restrict__ initb){
  const int gid = blockIdx.x*blockDim.x + threadIdx.x;   // 0..2047
  const int b = gid >> 10;
  const int n = (gid & 1023) * 2;
  size_t base = (size_t)b*NCH*NDIM + n;
  float c0 = 0.f, c1 = 0.f;
#pragma unroll 8
  for (int c = 0; c < NCH; ++c){
    float2 iv; iv.x = c0; iv.y = c1;
    *(float2*)(initb + base) = iv;
    float2 pp = *(const float2*)(P  + base);
    float2 hh = *(const float2*)(HL + base);
    c0 = pp.x*c0 + hh.x;
    c1 = pp.y*c1 + hh.y;
    base += NDIM;
  }
}

// ---------------- 5. apply: replay with true init, y in packed A-frag layout ----
__global__ void scan_apply_kernel(const unsigned short* __restrict__ abar,
                                  const unsigned short* __restrict__ bbar,
                                  const unsigned short* __restrict__ cf,
                                  const float* __restrict__ initb,
                                  unsigned short* __restrict__ ybp){
  const int n = blockIdx.x*512 + threadIdx.x*2;
  const int c = blockIdx.y;
  const int b = blockIdx.z;
  size_t io = ((size_t)(b*NCH + c))*NDIM + n;
  float2 iv = *(const float2*)(initb + io);
  float h0 = iv.x, h1 = iv.y;
  size_t base = ((size_t)(b*SS + c*CH))*NDIM + n;
  // packed y address: (t>>4)*32768 + (n>>5)*512 + ((n>>3)&3)*128 + (t&15)*8 + (n&7)
  const int nPart = ((n >> 5) << 9) + (((n >> 3) & 3) << 7) + (n & 7);
  int t = b*SS + c*CH;
#pragma unroll 8
  for (int s = 0; s < CH; ++s){
    ushort2 a2 = *(const ushort2*)(abar + base);
    ushort2 b2 = *(const ushort2*)(bbar + base);
    ushort2 c2 = *(const ushort2*)(cf   + base);
    h0 = b2f(a2.x)*h0 + b2f(b2.x);
    h1 = b2f(a2.y)*h1 + b2f(b2.y);
    ushort2 yv;
    yv.x = f2b(b2f(c2.x)*h0);
    yv.y = f2b(b2f(c2.y)*h1);
    *(ushort2*)(ybp + (size_t)(t >> 4)*32768 + nPart + (t & 15)*8) = yv;
    base += NDIM;
    ++t;
  }
}

// ---------------- 6. output projection ----------------
// grid (TT/64, DDIM/16), block 256 (4 waves). Wave: 16t x 16d, K=2048.
// All loads contiguous packed fragments.
__global__ void outproj_kernel(const unsigned short* __restrict__ ybp,
                               const unsigned short* __restrict__ Wop,
                               const float* __restrict__ b_out,
                               float* __restrict__ out){
  const int lane = threadIdx.x & 63;
  const int wv   = threadIdx.x >> 6;
  const int m    = lane & 15;
  const int q    = lane >> 4;
  const int tileT = blockIdx.x*4 + wv;
  const unsigned short* aP = ybp + (size_t)tileT*32768 + lane*8;
  const unsigned short* bP = Wop + (size_t)blockIdx.y*32768 + lane*8;

  floatx4 acc = {0.f,0.f,0.f,0.f};
#pragma unroll 8
  for (int kk = 0; kk < 64; ++kk){
    short8 af = *(const short8*)(aP + kk*512);
    short8 bf = *(const short8*)(bP + kk*512);
    acc = __builtin_amdgcn_mfma_f32_16x16x32_bf16(af, bf, acc, 0, 0, 0);
  }
  const int d = blockIdx.y*16 + m;
  const float bo = b_out[d];
#pragma unroll
  for (int r = 0; r < 4; ++r){
    int t = tileT*16 + q*4 + r;
    out[(size_t)t*DDIM + d] = acc[r] + bo;
  }
}

extern "C" void kernel_launch(void* const* d_in, const int* in_sizes, int n_in,
                              void* d_out, int out_size, void* d_ws, size_t ws_size,
                              hipStream_t stream) {
  const float* x     = (const float*)d_in[0];
  const float* W_B   = (const float*)d_in[1];
  const float* b_B   = (const float*)d_in[2];
  const float* W_C   = (const float*)d_in[3];
  const float* b_C   = (const float*)d_in[4];
  const float* W_dt  = (const float*)d_in[5];
  const float* b_dt  = (const float*)d_in[6];
  const float* A_log = (const float*)d_in[7];
  const float* W_out = (const float*)d_in[8];
  const float* b_out = (const float*)d_in[9];
  float* out = (float*)d_out;

  char* w = (char*)d_ws;
  unsigned short* xp    = (unsigned short*)(w + 0x0000000);  // 1 MB   (dead after proj)
  unsigned short* Wp3   = (unsigned short*)(w + 0x0100000);  // 1.5 MB (dead after proj)
  unsigned short* Wop   = (unsigned short*)(w + 0x0280000);  // 0.5 MB
  float*          Aval  = (float*)         (w + 0x0300000);  // 8 KB
  unsigned short* abar  = (unsigned short*)(w + 0x0310000);  // 16 MB
  unsigned short* bbar  = (unsigned short*)(w + 0x1310000);  // 16 MB
  unsigned short* cf    = (unsigned short*)(w + 0x2310000);  // 16 MB
  unsigned short* ybp   = (unsigned short*)(w + 0x3310000);  // 16 MB (packed A-frag)
  float*          HLbuf = (float*)         (w + 0x4310000);  // 1 MB
  float*          initb = (float*)         (w + 0x0000000);  // 1 MB  (reuses xp)
  float*          Pbuf  = (float*)         (w + 0x0100000);  // 1 MB  (reuses Wp3)
  // max offset 0x4410000 (~71.3 MB) — within round-1 footprint

  prep_kernel<<<384, 256, 0, stream>>>(
      x, W_B, W_C, W_dt, A_log, W_out, xp, Wp3, Wop, Aval);

  proj_kernel<<<dim3(TT/64, NDIM/64), 256, 0, stream>>>(
      xp, Wp3, b_B, b_dt, b_C, Aval, abar, bbar, cf);

  scan_local_kernel<<<dim3(NDIM/512, NCH, BB), 256, 0, stream>>>(
      abar, bbar, Pbuf, HLbuf);

  scan_carry_kernel<<<(BB*NDIM/2 + 255)/256, 256, 0, stream>>>(
      Pbuf, HLbuf, initb);

  scan_apply_kernel<<<dim3(NDIM/512, NCH, BB), 256, 0, stream>>>(
      abar, bbar, cf, initb, ybp);

  outproj_kernel<<<dim3(TT/64, DDIM/16), 256, 0, stream>>>(
      ybp, Wop, b_out, out);
}

// Round 3
// 143.388 us; speedup vs baseline: 1.6084x; 1.0136x over previous
//
#include <hip/hip_runtime.h>

// Rec1_43748536877661 — diagonal SSM block, MI355X gfx950.
// B=2,S=2048,D=128,N=2048. fp32 in/out, bf16 MFMA compute (tol 2.14e-2).
// R3: recompute-proj chunked scan. a/b/c never materialized; 16-token tile scan
// done in-register via 4 shuffle steps (D.col = t = lane&15). 5 kernels:
//  1. prep       pack x,W_B/dt/C,W_out into MFMA fragment-linear bf16; Aval
//  2. projscan1  proj(B,dt) + tile shuffle-scan -> PH (prod_a, h_local) 4MB
//  3. carry      compose 128 tiles per (b,n) chain -> per-tile init h0 (2MB)
//  4. projscan2  proj(B,dt,C) + scan + init -> y (bf16, packed A-frag) 16MB
//  5. outproj    y @ W_out^T, 1 t-tile/block, waves split K, LDS reduce

#define BB 2
#define SS 2048
#define DDIM 128
#define NDIM 2048
#define TT (BB*SS)        // 4096 tokens
#define NTILE (TT/16)     // 256 t-tiles
#define TPB 128           // tiles per batch

typedef short short8 __attribute__((ext_vector_type(8)));
typedef float floatx4 __attribute__((ext_vector_type(4)));

__device__ __forceinline__ unsigned short f2b(float f){
  unsigned u = __float_as_uint(f);
  u += 0x7FFFu + ((u >> 16) & 1u);
  return (unsigned short)(u >> 16);
}
__device__ __forceinline__ float softplus_f(float v){
  return v > 15.f ? v : __logf(1.f + __expf(v));
}
__device__ __forceinline__ void pack8(const float* __restrict__ s,
                                      unsigned short* __restrict__ d){
  floatx4 v0 = *(const floatx4*)s;
  floatx4 v1 = *(const floatx4*)(s + 4);
  short8 r;
  r[0]=(short)f2b(v0[0]); r[1]=(short)f2b(v0[1]); r[2]=(short)f2b(v0[2]); r[3]=(short)f2b(v0[3]);
  r[4]=(short)f2b(v1[0]); r[5]=(short)f2b(v1[1]); r[6]=(short)f2b(v1[2]); r[7]=(short)f2b(v1[3]);
  *(short8*)d = r;
}

// ---------------- 1. prep: pack to MFMA fragment-linear layouts ----------------
__global__ void prep_kernel(const float* __restrict__ x,
                            const float* __restrict__ W_B,
                            const float* __restrict__ W_C,
                            const float* __restrict__ W_dt,
                            const float* __restrict__ A_log,
                            const float* __restrict__ W_out,
                            unsigned short* __restrict__ xp,
                            unsigned short* __restrict__ Wp3,
                            unsigned short* __restrict__ Wop,
                            float* __restrict__ Aval){
  const int gid = blockIdx.x * blockDim.x + threadIdx.x;   // 0..98303
  if (gid < 2048) Aval[gid] = -__expf(A_log[gid]);
  if (gid < 65536){                               // x: 256 t-tiles, K=128
    int g = gid, tile = g >> 8, kk = (g >> 6) & 3, lane = g & 63;
    int q = lane >> 4, m = lane & 15;
    pack8(x + (size_t)(tile*16 + m)*DDIM + kk*32 + q*8, xp + (size_t)g*8);
  }
  if (gid < 98304){                               // W_B/W_dt/W_C: 128 n-tiles each
    int mat = gid >> 15, g = gid & 32767;
    const float* W = (mat == 0) ? W_B : (mat == 1 ? W_dt : W_C);
    int tile = g >> 8, kk = (g >> 6) & 3, lane = g & 63;
    int q = lane >> 4, m = lane & 15;
    pack8(W + (size_t)(tile*16 + m)*DDIM + kk*32 + q*8,
          Wp3 + (size_t)mat*262144 + (size_t)g*8);
  }
  if (gid < 32768){                               // W_out: 8 d-tiles, K=2048
    int g = gid, tile = g >> 12, kk = (g >> 6) & 63, lane = g & 63;
    int q = lane >> 4, m = lane & 15;
    pack8(W_out + (size_t)(tile*16 + m)*NDIM + kk*32 + q*8, Wop + (size_t)g*8);
  }
}

// ---------------- 2. pass 1: proj(B,dt) + tile scan -> PH ----------------
// grid (TT/64, NDIM/64), block 256. mfma(Wfrag,xfrag): D.row->n(q*4+r), D.col->t(m).
__global__ void projscan1_kernel(const unsigned short* __restrict__ xp,
                                 const unsigned short* __restrict__ Wp3,
                                 const float* __restrict__ b_B,
                                 const float* __restrict__ b_dt,
                                 const float* __restrict__ Aval,
                                 float2* __restrict__ PH){
  __shared__ unsigned short sW[2*8192];
  const int tid  = threadIdx.x;
  const int lane = tid & 63;
  const int wv   = tid >> 6;
  const int m    = lane & 15;
  const int q    = lane >> 4;

#pragma unroll
  for (int mat = 0; mat < 2; ++mat){
    const unsigned short* src = Wp3 + (size_t)mat*262144 + (size_t)blockIdx.y*8192;
    unsigned short* dst = sW + mat*8192;
#pragma unroll
    for (int i = 0; i < 4; ++i){
      int e = (i*256 + tid) * 8;
      *(short8*)(dst + e) = *(const short8*)(src + e);
    }
  }
  __syncthreads();

  const int tileT = blockIdx.x*4 + wv;
  short8 xf[4];
#pragma unroll
  for (int kk = 0; kk < 4; ++kk)
    xf[kk] = *(const short8*)(xp + (size_t)tileT*2048 + kk*512 + lane*8);

  floatx4 acc[2][4];
#pragma unroll
  for (int mat = 0; mat < 2; ++mat)
#pragma unroll
    for (int nt = 0; nt < 4; ++nt)
      acc[mat][nt] = (floatx4){0.f,0.f,0.f,0.f};
#pragma unroll
  for (int mat = 0; mat < 2; ++mat)
#pragma unroll
    for (int nt = 0; nt < 4; ++nt)
#pragma unroll
      for (int kk = 0; kk < 4; ++kk){
        short8 wf = *(const short8*)(sW + mat*8192 + nt*2048 + kk*512 + lane*8);
        acc[mat][nt] = __builtin_amdgcn_mfma_f32_16x16x32_bf16(wf, xf[kk], acc[mat][nt], 0, 0, 0);
      }

  const int n0 = blockIdx.y*64;
#pragma unroll
  for (int nt = 0; nt < 4; ++nt){
    const int nb = n0 + nt*16 + q*4;
    floatx4 bB4 = *(const floatx4*)(b_B  + nb);
    floatx4 bD4 = *(const floatx4*)(b_dt + nb);
    floatx4 A4  = *(const floatx4*)(Aval + nb);
    float Ar[4], Br[4];
#pragma unroll
    for (int r = 0; r < 4; ++r){
      float dtv = softplus_f(acc[1][nt][r] + bD4[r]);
      Ar[r] = __expf(dtv * A4[r]);
      Br[r] = dtv * (acc[0][nt][r] + bB4[r]);
    }
    // Hillis-Steele affine scan along t (lanes m=0..15 within q-group)
#pragma unroll
    for (int off = 1; off < 16; off <<= 1){
#pragma unroll
      for (int r = 0; r < 4; ++r){
        float pA = __shfl(Ar[r], (lane - off) & 63, 64);
        float pB = __shfl(Br[r], (lane - off) & 63, 64);
        if (m >= off){ Br[r] = Ar[r]*pB + Br[r]; Ar[r] *= pA; }
      }
    }
    if (m == 15){
#pragma unroll
      for (int r = 0; r < 4; ++r){
        float2 ph; ph.x = Ar[r]; ph.y = Br[r];
        PH[(size_t)tileT*NDIM + nb + r] = ph;
      }
    }
  }
}

// ---------------- 3. carry: compose tiles along each (b,n) chain ----------------
__global__ void carry_kernel(const float2* __restrict__ PH,
                             float* __restrict__ initb){
  const int gid = blockIdx.x*blockDim.x + threadIdx.x;   // 0..4095
  const int b = gid >> 11;
  const int n = gid & 2047;
  size_t base = (size_t)b*TPB*NDIM + n;
  float h = 0.f;
#pragma unroll 8
  for (int j = 0; j < TPB; ++j){
    initb[base] = h;
    float2 ph = PH[base];
    h = ph.x*h + ph.y;
    base += NDIM;
  }
}

// ---------------- 4. pass 2: proj(B,dt,C) + scan + init -> y packed ----------------
__global__ void projscan2_kernel(const unsigned short* __restrict__ xp,
                                 const unsigned short* __restrict__ Wp3,
                                 const float* __restrict__ b_B,
                                 const float* __restrict__ b_dt,
                                 const float* __restrict__ b_C,
                                 const float* __restrict__ Aval,
                                 const float* __restrict__ initb,
                                 unsigned short* __restrict__ ybp){
  __shared__ unsigned short sW[3*8192];
  const int tid  = threadIdx.x;
  const int lane = tid & 63;
  const int wv   = tid >> 6;
  const int m    = lane & 15;
  const int q    = lane >> 4;

#pragma unroll
  for (int mat = 0; mat < 3; ++mat){
    const unsigned short* src = Wp3 + (size_t)mat*262144 + (size_t)blockIdx.y*8192;
    unsigned short* dst = sW + mat*8192;
#pragma unroll
    for (int i = 0; i < 4; ++i){
      int e = (i*256 + tid) * 8;
      *(short8*)(dst + e) = *(const short8*)(src + e);
    }
  }
  __syncthreads();

  const int tileT = blockIdx.x*4 + wv;
  short8 xf[4];
#pragma unroll
  for (int kk = 0; kk < 4; ++kk)
    xf[kk] = *(const short8*)(xp + (size_t)tileT*2048 + kk*512 + lane*8);

  floatx4 acc[3][4];
#pragma unroll
  for (int mat = 0; mat < 3; ++mat)
#pragma unroll
    for (int nt = 0; nt < 4; ++nt)
      acc[mat][nt] = (floatx4){0.f,0.f,0.f,0.f};
#pragma unroll
  for (int mat = 0; mat < 3; ++mat)
#pragma unroll
    for (int nt = 0; nt < 4; ++nt)
#pragma unroll
      for (int kk = 0; kk < 4; ++kk){
        short8 wf = *(const short8*)(sW + mat*8192 + nt*2048 + kk*512 + lane*8);
        acc[mat][nt] = __builtin_amdgcn_mfma_f32_16x16x32_bf16(wf, xf[kk], acc[mat][nt], 0, 0, 0);
      }

  const int n0 = blockIdx.y*64;
#pragma unroll
  for (int nt = 0; nt < 4; ++nt){
    const int nb = n0 + nt*16 + q*4;
    floatx4 bB4 = *(const floatx4*)(b_B  + nb);
    floatx4 bD4 = *(const floatx4*)(b_dt + nb);
    floatx4 bC4 = *(const floatx4*)(b_C  + nb);
    floatx4 A4  = *(const floatx4*)(Aval + nb);
    floatx4 iv4 = *(const floatx4*)(initb + (size_t)tileT*NDIM + nb);
    float Ar[4], Br[4], Cc[4];
#pragma unroll
    for (int r = 0; r < 4; ++r){
      float dtv = softplus_f(acc[1][nt][r] + bD4[r]);
      Ar[r] = __expf(dtv * A4[r]);
      Br[r] = dtv * (acc[0][nt][r] + bB4[r]);
      Cc[r] = acc[2][nt][r] + bC4[r];
    }
#pragma unroll
    for (int off = 1; off < 16; off <<= 1){
#pragma unroll
      for (int r = 0; r < 4; ++r){
        float pA = __shfl(Ar[r], (lane - off) & 63, 64);
        float pB = __shfl(Br[r], (lane - off) & 63, 64);
        if (m >= off){ Br[r] = Ar[r]*pB + Br[r]; Ar[r] *= pA; }
      }
    }
    ushort4 yv;
#pragma unroll
    for (int r = 0; r < 4; ++r){
      float h = Ar[r]*iv4[r] + Br[r];
      ((unsigned short*)&yv)[r] = f2b(Cc[r]*h);
    }
    // packed A-frag (K=2048): addr = tile*32768 + (n>>5)*512 + (((n>>3)&3)*16+m)*8 + (n&7)
    const int npos = n0 + nt*16 + q*4;
    size_t addr = (size_t)tileT*32768 + (size_t)(npos >> 5)*512
                + (size_t)((((npos >> 3) & 3) << 4) + m)*8 + (npos & 7);
    *(ushort4*)(ybp + addr) = yv;
  }
}

// ---------------- 5. output projection ----------------
// grid NTILE=256, block 256. Wave wv handles kk in [wv*16, wv*16+16), all 8 d-tiles.
__global__ void outproj_kernel(const unsigned short* __restrict__ ybp,
                               const unsigned short* __restrict__ Wop,
                               const float* __restrict__ b_out,
                               float* __restrict__ out){
  __shared__ float red[4*2048];
  const int tid  = threadIdx.x;
  const int lane = tid & 63;
  const int wv   = tid >> 6;
  const int m    = lane & 15;
  const int q    = lane >> 4;
  const int tile = blockIdx.x;

  floatx4 acc[8];
#pragma unroll
  for (int dt = 0; dt < 8; ++dt) acc[dt] = (floatx4){0.f,0.f,0.f,0.f};

  const unsigned short* aP = ybp + (size_t)tile*32768 + lane*8;
  const unsigned short* bP = Wop + (size_t)lane*8;
#pragma unroll 4
  for (int kk = wv*16; kk < wv*16 + 16; ++kk){
    short8 af = *(const short8*)(aP + (size_t)kk*512);
#pragma unroll
    for (int dt = 0; dt < 8; ++dt){
      short8 bf = *(const short8*)(bP + (size_t)dt*32768 + (size_t)kk*512);
      acc[dt] = __builtin_amdgcn_mfma_f32_16x16x32_bf16(af, bf, acc[dt], 0, 0, 0);
    }
  }
#pragma unroll
  for (int dt = 0; dt < 8; ++dt)
#pragma unroll
    for (int r = 0; r < 4; ++r)
      red[wv*2048 + (q*4 + r)*128 + dt*16 + m] = acc[dt][r];
  __syncthreads();
#pragma unroll
  for (int i = 0; i < 8; ++i){
    int idx = i*256 + tid;                        // 0..2047 = tl*128 + d
    float s = red[idx] + red[2048 + idx] + red[4096 + idx] + red[6144 + idx];
    int tl = idx >> 7, d = idx & 127;
    out[(size_t)(tile*16 + tl)*DDIM + d] = s + b_out[d];
  }
}

extern "C" void kernel_launch(void* const* d_in, const int* in_sizes, int n_in,
                              void* d_out, int out_size, void* d_ws, size_t ws_size,
                              hipStream_t stream) {
  const float* x     = (const float*)d_in[0];
  const float* W_B   = (const float*)d_in[1];
  const float* b_B   = (const float*)d_in[2];
  const float* W_C   = (const float*)d_in[3];
  const float* b_C   = (const float*)d_in[4];
  const float* W_dt  = (const float*)d_in[5];
  const float* b_dt  = (const float*)d_in[6];
  const float* A_log = (const float*)d_in[7];
  const float* W_out = (const float*)d_in[8];
  const float* b_out = (const float*)d_in[9];
  float* out = (float*)d_out;

  char* w = (char*)d_ws;
  unsigned short* xp    = (unsigned short*)(w + 0x0000000);  // 1 MB
  unsigned short* Wp3   = (unsigned short*)(w + 0x0100000);  // 1.5 MB
  unsigned short* Wop   = (unsigned short*)(w + 0x0280000);  // 0.5 MB
  float*          Aval  = (float*)         (w + 0x0300000);  // 8 KB
  float2*         PH    = (float2*)        (w + 0x0310000);  // 4 MB
  float*          initb = (float*)         (w + 0x0710000);  // 2 MB
  unsigned short* ybp   = (unsigned short*)(w + 0x0910000);  // 16 MB
  // total ~25.6 MB

  prep_kernel<<<384, 256, 0, stream>>>(
      x, W_B, W_C, W_dt, A_log, W_out, xp, Wp3, Wop, Aval);

  projscan1_kernel<<<dim3(TT/64, NDIM/64), 256, 0, stream>>>(
      xp, Wp3, b_B, b_dt, Aval, PH);

  carry_kernel<<<16, 256, 0, stream>>>(PH, initb);

  projscan2_kernel<<<dim3(TT/64, NDIM/64), 256, 0, stream>>>(
      xp, Wp3, b_B, b_dt, b_C, Aval, initb, ybp);

  outproj_kernel<<<NTILE, 256, 0, stream>>>(ybp, Wop, b_out, out);
}

// Round 4
// 127.421 us; speedup vs baseline: 1.8099x; 1.1253x over previous
//
#include <hip/hip_runtime.h>

// Rec1_43748536877661 — diagonal SSM block, MI355X gfx950.
// B=2,S=2048,D=128,N=2048. fp32 in/out, bf16 MFMA compute (tol 2.14e-2).
// R4: orientation mfma(x,W) => D.row->t (in-register), scan = serial-4 + 2
// shuffle steps (24 bperm/thread vs 128); LDS-transpose coalesced y stores;
// block-parallel 2-level carry.
//  1. prep       pack x,W_B/dt/C,W_out fragment-linear bf16; Aval=-exp(A_log)
//  2. projscan1  proj(B,dt) + tile scan -> PH[256][2048] (prod_a, h_local)
//  3. carry      2-level scan over 128 tiles/chain -> per-tile init h0
//  4. projscan2  proj(B,dt,C) + scan + init -> ybp (bf16 A-frag packed)
//  5. outproj    y @ W_out^T + b_out -> fp32 out

#define BB 2
#define SS 2048
#define DDIM 128
#define NDIM 2048
#define TT (BB*SS)        // 4096 tokens
#define NTILE (TT/16)     // 256 t-tiles
#define TPB 128           // t-tiles per batch

typedef short short8 __attribute__((ext_vector_type(8)));
typedef float floatx4 __attribute__((ext_vector_type(4)));

__device__ __forceinline__ unsigned short f2b(float f){
  unsigned u = __float_as_uint(f);
  u += 0x7FFFu + ((u >> 16) & 1u);
  return (unsigned short)(u >> 16);
}
__device__ __forceinline__ float softplus_f(float v){
  return v > 15.f ? v : __logf(1.f + __expf(v));
}
__device__ __forceinline__ void pack8(const float* __restrict__ s,
                                      unsigned short* __restrict__ d){
  floatx4 v0 = *(const floatx4*)s;
  floatx4 v1 = *(const floatx4*)(s + 4);
  short8 r;
  r[0]=(short)f2b(v0[0]); r[1]=(short)f2b(v0[1]); r[2]=(short)f2b(v0[2]); r[3]=(short)f2b(v0[3]);
  r[4]=(short)f2b(v1[0]); r[5]=(short)f2b(v1[1]); r[6]=(short)f2b(v1[2]); r[7]=(short)f2b(v1[3]);
  *(short8*)d = r;
}

// ---------------- 1. prep ----------------
__global__ void prep_kernel(const float* __restrict__ x,
                            const float* __restrict__ W_B,
                            const float* __restrict__ W_C,
                            const float* __restrict__ W_dt,
                            const float* __restrict__ A_log,
                            const float* __restrict__ W_out,
                            unsigned short* __restrict__ xp,
                            unsigned short* __restrict__ Wp3,
                            unsigned short* __restrict__ Wop,
                            float* __restrict__ Aval){
  const int gid = blockIdx.x * blockDim.x + threadIdx.x;   // 0..98303
  if (gid < 2048) Aval[gid] = -__expf(A_log[gid]);
  if (gid < 65536){                               // x: 256 t-tiles, K=128
    int g = gid, tile = g >> 8, kk = (g >> 6) & 3, lane = g & 63;
    int q = lane >> 4, m = lane & 15;
    pack8(x + (size_t)(tile*16 + m)*DDIM + kk*32 + q*8, xp + (size_t)g*8);
  }
  if (gid < 98304){                               // W_B/W_dt/W_C
    int mat = gid >> 15, g = gid & 32767;
    const float* W = (mat == 0) ? W_B : (mat == 1 ? W_dt : W_C);
    int tile = g >> 8, kk = (g >> 6) & 3, lane = g & 63;
    int q = lane >> 4, m = lane & 15;
    pack8(W + (size_t)(tile*16 + m)*DDIM + kk*32 + q*8,
          Wp3 + (size_t)mat*262144 + (size_t)g*8);
  }
  if (gid < 32768){                               // W_out: 8 d-tiles, K=2048
    int g = gid, tile = g >> 12, kk = (g >> 6) & 63, lane = g & 63;
    int q = lane >> 4, m = lane & 15;
    pack8(W_out + (size_t)(tile*16 + m)*NDIM + kk*32 + q*8, Wop + (size_t)g*8);
  }
}

// ---------------- 2. projscan1: proj(B,dt) + tile scan -> PH ----------------
// grid (TT/64, NDIM/64), block 256. mfma(xf,wf): D.row->t(q*4+r), D.col->n(m).
__global__ void projscan1_kernel(const unsigned short* __restrict__ xp,
                                 const unsigned short* __restrict__ Wp3,
                                 const float* __restrict__ b_B,
                                 const float* __restrict__ b_dt,
                                 const float* __restrict__ Aval,
                                 float2* __restrict__ PH){
  __shared__ unsigned short sW[2*8192];
  const int tid  = threadIdx.x;
  const int lane = tid & 63;
  const int wv   = tid >> 6;
  const int m    = lane & 15;
  const int q    = lane >> 4;

#pragma unroll
  for (int mat = 0; mat < 2; ++mat){
    const unsigned short* src = Wp3 + (size_t)mat*262144 + (size_t)blockIdx.y*8192;
    unsigned short* dst = sW + mat*8192;
#pragma unroll
    for (int i = 0; i < 4; ++i){
      int e = (i*256 + tid) * 8;
      *(short8*)(dst + e) = *(const short8*)(src + e);
    }
  }
  __syncthreads();

  const int tileT = blockIdx.x*4 + wv;
  short8 xf[4];
#pragma unroll
  for (int kk = 0; kk < 4; ++kk)
    xf[kk] = *(const short8*)(xp + (size_t)tileT*2048 + kk*512 + lane*8);

  floatx4 acc[2][4];
#pragma unroll
  for (int mat = 0; mat < 2; ++mat)
#pragma unroll
    for (int nt = 0; nt < 4; ++nt)
      acc[mat][nt] = (floatx4){0.f,0.f,0.f,0.f};
#pragma unroll
  for (int nt = 0; nt < 4; ++nt)
#pragma unroll
    for (int kk = 0; kk < 4; ++kk){
      short8 wB = *(const short8*)(sW +          nt*2048 + kk*512 + lane*8);
      short8 wD = *(const short8*)(sW + 8192 +   nt*2048 + kk*512 + lane*8);
      acc[0][nt] = __builtin_amdgcn_mfma_f32_16x16x32_bf16(xf[kk], wB, acc[0][nt], 0, 0, 0);
      acc[1][nt] = __builtin_amdgcn_mfma_f32_16x16x32_bf16(xf[kk], wD, acc[1][nt], 0, 0, 0);
    }

  const int n0 = blockIdx.y*64;
#pragma unroll
  for (int nt = 0; nt < 4; ++nt){
    const int n = n0 + nt*16 + m;
    const float bB = b_B[n], bD = b_dt[n], Av = Aval[n];
    float Ar[4], Br[4];
#pragma unroll
    for (int r = 0; r < 4; ++r){
      float dtv = softplus_f(acc[1][nt][r] + bD);
      Ar[r] = __expf(dtv * Av);
      Br[r] = dtv * (acc[0][nt][r] + bB);
    }
    // serial compose over 4 in-register t
    float P = Ar[0], H = Br[0];
#pragma unroll
    for (int r = 1; r < 4; ++r){ H = Ar[r]*H + Br[r]; P *= Ar[r]; }
    // cross-q inclusive scan (2 steps)
    float pp = __shfl(P, (lane - 16) & 63, 64);
    float hh = __shfl(H, (lane - 16) & 63, 64);
    if (q >= 1){ H = P*hh + H; P = P*pp; }
    pp = __shfl(P, (lane - 32) & 63, 64);
    hh = __shfl(H, (lane - 32) & 63, 64);
    if (q >= 2){ H = P*hh + H; P = P*pp; }
    if (q == 3){
      float2 ph; ph.x = P; ph.y = H;
      PH[(size_t)tileT*NDIM + n] = ph;
    }
  }
}

// ---------------- 3. carry: 2-level block-parallel scan ----------------
// grid 128 blocks x 256 threads. Block = 32 chains (one b, 32 consecutive n);
// thread (c=tid&31, s=tid>>5) handles segment s (16 tiles) of chain c.
__global__ void carry_kernel(const float2* __restrict__ PH,
                             float* __restrict__ initb){
  __shared__ float sP[8][32], sH[8][32], eP[8][32], eH[8][32];
  const int tid = threadIdx.x;
  const int c = tid & 31;
  const int s = tid >> 5;
  const int b = blockIdx.x >> 6;
  const int n = (blockIdx.x & 63)*32 + c;

  float Pj[16], Hj[16];
  size_t base = ((size_t)(b*TPB + s*16))*NDIM + n;
#pragma unroll
  for (int j = 0; j < 16; ++j){
    float2 ph = PH[base + (size_t)j*NDIM];
    Pj[j] = ph.x; Hj[j] = ph.y;
  }
  float P = Pj[0], H = Hj[0];
#pragma unroll
  for (int j = 1; j < 16; ++j){ H = Pj[j]*H + Hj[j]; P *= Pj[j]; }
  sP[s][c] = P; sH[s][c] = H;
  __syncthreads();
  if (tid < 32){
    float p = 1.f, h = 0.f;
#pragma unroll
    for (int ss = 0; ss < 8; ++ss){
      eP[ss][tid] = p; eH[ss][tid] = h;
      h = sP[ss][tid]*h + sH[ss][tid];
      p = sP[ss][tid]*p;
    }
  }
  __syncthreads();
  float h = eH[s][c];          // chain init is 0 => seg init = eH
#pragma unroll
  for (int j = 0; j < 16; ++j){
    initb[base + (size_t)j*NDIM] = h;
    h = Pj[j]*h + Hj[j];
  }
}

// ---------------- 4. projscan2: proj(B,dt,C) + scan + init -> ybp ----------------
__global__ void projscan2_kernel(const unsigned short* __restrict__ xp,
                                 const unsigned short* __restrict__ Wp3,
                                 const float* __restrict__ b_B,
                                 const float* __restrict__ b_dt,
                                 const float* __restrict__ b_C,
                                 const float* __restrict__ Aval,
                                 const float* __restrict__ initb,
                                 unsigned short* __restrict__ ybp){
  __shared__ unsigned short sW[3*8192];
  __shared__ unsigned short sYT[4][16*40];   // per-wave transpose tile [t][n], pad 40
  const int tid  = threadIdx.x;
  const int lane = tid & 63;
  const int wv   = tid >> 6;
  const int m    = lane & 15;
  const int q    = lane >> 4;

#pragma unroll
  for (int mat = 0; mat < 3; ++mat){
    const unsigned short* src = Wp3 + (size_t)mat*262144 + (size_t)blockIdx.y*8192;
    unsigned short* dst = sW + mat*8192;
#pragma unroll
    for (int i = 0; i < 4; ++i){
      int e = (i*256 + tid) * 8;
      *(short8*)(dst + e) = *(const short8*)(src + e);
    }
  }
  __syncthreads();

  const int tileT = blockIdx.x*4 + wv;
  short8 xf[4];
#pragma unroll
  for (int kk = 0; kk < 4; ++kk)
    xf[kk] = *(const short8*)(xp + (size_t)tileT*2048 + kk*512 + lane*8);

  floatx4 acc[3][4];
#pragma unroll
  for (int mat = 0; mat < 3; ++mat)
#pragma unroll
    for (int nt = 0; nt < 4; ++nt)
      acc[mat][nt] = (floatx4){0.f,0.f,0.f,0.f};
#pragma unroll
  for (int nt = 0; nt < 4; ++nt)
#pragma unroll
    for (int kk = 0; kk < 4; ++kk){
      short8 wB = *(const short8*)(sW +           nt*2048 + kk*512 + lane*8);
      short8 wD = *(const short8*)(sW + 8192 +    nt*2048 + kk*512 + lane*8);
      short8 wC = *(const short8*)(sW + 16384 +   nt*2048 + kk*512 + lane*8);
      acc[0][nt] = __builtin_amdgcn_mfma_f32_16x16x32_bf16(xf[kk], wB, acc[0][nt], 0, 0, 0);
      acc[1][nt] = __builtin_amdgcn_mfma_f32_16x16x32_bf16(xf[kk], wD, acc[1][nt], 0, 0, 0);
      acc[2][nt] = __builtin_amdgcn_mfma_f32_16x16x32_bf16(xf[kk], wC, acc[2][nt], 0, 0, 0);
    }

  const int n0 = blockIdx.y*64;
  unsigned short ybuf[16];
#pragma unroll
  for (int nt = 0; nt < 4; ++nt){
    const int n = n0 + nt*16 + m;
    const float bB = b_B[n], bD = b_dt[n], bC = b_C[n], Av = Aval[n];
    const float iv = initb[(size_t)tileT*NDIM + n];
    float Ar[4], Br[4], Cc[4];
#pragma unroll
    for (int r = 0; r < 4; ++r){
      float dtv = softplus_f(acc[1][nt][r] + bD);
      Ar[r] = __expf(dtv * Av);
      Br[r] = dtv * (acc[0][nt][r] + bB);
      Cc[r] = acc[2][nt][r] + bC;
    }
    float P = Ar[0], H = Br[0];
#pragma unroll
    for (int r = 1; r < 4; ++r){ H = Ar[r]*H + Br[r]; P *= Ar[r]; }
    float pp = __shfl(P, (lane - 16) & 63, 64);
    float hh = __shfl(H, (lane - 16) & 63, 64);
    if (q >= 1){ H = P*hh + H; P = P*pp; }
    pp = __shfl(P, (lane - 32) & 63, 64);
    hh = __shfl(H, (lane - 32) & 63, 64);
    if (q >= 2){ H = P*hh + H; P = P*pp; }
    // exclusive init for this q-group = inclusive of q-1 (identity for q=0)
    float pe = __shfl(P, (lane - 16) & 63, 64);
    float he = __shfl(H, (lane - 16) & 63, 64);
    if (q == 0){ pe = 1.f; he = 0.f; }
    float h = pe*iv + he;
#pragma unroll
    for (int r = 0; r < 4; ++r){
      h = Ar[r]*h + Br[r];
      ybuf[nt*4 + r] = f2b(Cc[r]*h);
    }
  }
  // transpose D-layout (t in regs/q) -> A-frag layout via per-wave LDS, 2 pairs
#pragma unroll
  for (int p = 0; p < 2; ++p){
#pragma unroll
    for (int nt2 = 0; nt2 < 2; ++nt2){
      const int nt = 2*p + nt2;
#pragma unroll
      for (int r = 0; r < 4; ++r)
        sYT[wv][(q*4 + r)*40 + nt2*16 + m] = ybuf[nt*4 + r];
    }
    short8 af = *(const short8*)&sYT[wv][m*40 + q*8];
    const int kchunk = blockIdx.y*2 + p;
    *(short8*)(ybp + (size_t)tileT*32768 + (size_t)kchunk*512 + lane*8) = af;
  }
}

// ---------------- 5. output projection ----------------
// grid NTILE=256, block 256. Wave wv: kk in [wv*16, wv*16+16), all 8 d-tiles.
__global__ void outproj_kernel(const unsigned short* __restrict__ ybp,
                               const unsigned short* __restrict__ Wop,
                               const float* __restrict__ b_out,
                               float* __restrict__ out){
  __shared__ float red[4*2048];
  const int tid  = threadIdx.x;
  const int lane = tid & 63;
  const int wv   = tid >> 6;
  const int m    = lane & 15;
  const int q    = lane >> 4;
  const int tile = blockIdx.x;

  floatx4 acc[8];
#pragma unroll
  for (int dt = 0; dt < 8; ++dt) acc[dt] = (floatx4){0.f,0.f,0.f,0.f};

  const unsigned short* aP = ybp + (size_t)tile*32768 + lane*8;
  const unsigned short* bP = Wop + (size_t)lane*8;
#pragma unroll 4
  for (int kk = wv*16; kk < wv*16 + 16; ++kk){
    short8 af = *(const short8*)(aP + (size_t)kk*512);
#pragma unroll
    for (int dt = 0; dt < 8; ++dt){
      short8 bf = *(const short8*)(bP + (size_t)dt*32768 + (size_t)kk*512);
      acc[dt] = __builtin_amdgcn_mfma_f32_16x16x32_bf16(af, bf, acc[dt], 0, 0, 0);
    }
  }
#pragma unroll
  for (int dt = 0; dt < 8; ++dt)
#pragma unroll
    for (int r = 0; r < 4; ++r)
      red[wv*2048 + (q*4 + r)*128 + dt*16 + m] = acc[dt][r];
  __syncthreads();
#pragma unroll
  for (int i = 0; i < 8; ++i){
    int idx = i*256 + tid;                        // 0..2047 = tl*128 + d
    float s = red[idx] + red[2048 + idx] + red[4096 + idx] + red[6144 + idx];
    int tl = idx >> 7, d = idx & 127;
    out[(size_t)(tile*16 + tl)*DDIM + d] = s + b_out[d];
  }
}

extern "C" void kernel_launch(void* const* d_in, const int* in_sizes, int n_in,
                              void* d_out, int out_size, void* d_ws, size_t ws_size,
                              hipStream_t stream) {
  const float* x     = (const float*)d_in[0];
  const float* W_B   = (const float*)d_in[1];
  const float* b_B   = (const float*)d_in[2];
  const float* W_C   = (const float*)d_in[3];
  const float* b_C   = (const float*)d_in[4];
  const float* W_dt  = (const float*)d_in[5];
  const float* b_dt  = (const float*)d_in[6];
  const float* A_log = (const float*)d_in[7];
  const float* W_out = (const float*)d_in[8];
  const float* b_out = (const float*)d_in[9];
  float* out = (float*)d_out;

  char* w = (char*)d_ws;
  unsigned short* xp    = (unsigned short*)(w + 0x0000000);  // 1 MB
  unsigned short* Wp3   = (unsigned short*)(w + 0x0100000);  // 1.5 MB
  unsigned short* Wop   = (unsigned short*)(w + 0x0280000);  // 0.5 MB
  float*          Aval  = (float*)         (w + 0x0300000);  // 8 KB
  float2*         PH    = (float2*)        (w + 0x0310000);  // 4 MB
  float*          initb = (float*)         (w + 0x0710000);  // 2 MB
  unsigned short* ybp   = (unsigned short*)(w + 0x0910000);  // 16 MB

  prep_kernel<<<384, 256, 0, stream>>>(
      x, W_B, W_C, W_dt, A_log, W_out, xp, Wp3, Wop, Aval);

  projscan1_kernel<<<dim3(TT/64, NDIM/64), 256, 0, stream>>>(
      xp, Wp3, b_B, b_dt, Aval, PH);

  carry_kernel<<<128, 256, 0, stream>>>(PH, initb);

  projscan2_kernel<<<dim3(TT/64, NDIM/64), 256, 0, stream>>>(
      xp, Wp3, b_B, b_dt, b_C, Aval, initb, ybp);

  outproj_kernel<<<NTILE, 256, 0, stream>>>(ybp, Wop, b_out, out);
}